// Round 1
// baseline (487.400 us; speedup 1.0000x reference)
//
#include <hip/hip_runtime.h>
#include <math.h>

#define N_STATIONS 100000
#define N_TIME     1000
#define K_NEIGH    8
#define SPB        50      // stations per block; 100000 / 50 = 2000 blocks

// Block = 256 threads. Threads 0..249 each own 4 contiguous time indices
// (t = 4*tid..4*tid+3), so one float4 store per station covers the row.
__global__ __launch_bounds__(256) void insar_kernel(
    const float* __restrict__ time_vector,      // (1000,)
    const float* __restrict__ constant_offset,  // (100000,)
    const float* __restrict__ linear_trend,     // (100000,)
    const float* __restrict__ amps,             // (100000,4)
    const float* __restrict__ phases,           // (100000,4)
    const int*   __restrict__ nbr_idx,          // (100000,8)
    const float* __restrict__ nbr_w,            // (100000,8)
    const float* __restrict__ periods,          // (4,)
    float*       __restrict__ out)              // (100000,1000)
{
    __shared__ float lds_cs[SPB * 4];   // amp_s * cos(ph_s)
    __shared__ float lds_cc[SPB * 4];   // amp_s * sin(ph_s)
    __shared__ float lds_off[SPB];
    __shared__ float lds_tr[SPB];

    const int tid = threadIdx.x;
    const int n0  = blockIdx.x * SPB;
    const float TWO_PI = 6.28318530717958647692f;

    // ---- Phase A: per-thread sin/cos time tables (registers only) ----
    float t4[4];
    float stab[4][4], ctab[4][4];   // [harmonic][j]
    if (tid < 250) {
        const float4 tv = *(const float4*)(time_vector + 4 * tid);
        t4[0] = tv.x; t4[1] = tv.y; t4[2] = tv.z; t4[3] = tv.w;
#pragma unroll
        for (int i = 0; i < 4; ++i) {
            const float w = TWO_PI / periods[i];   // 2*pi*freq_i
#pragma unroll
            for (int j = 0; j < 4; ++j) {
                sincosf(w * t4[j], &stab[i][j], &ctab[i][j]);
            }
        }
    }

    // ---- Phase B: neighbor smoothing -> coefficients in LDS ----
    if (tid < SPB * 4) {                 // 200 threads: one (station, comp) each
        const int s = tid >> 2;
        const int c = tid & 3;
        const int n = n0 + s;
        const float a0 = amps[n * 4 + c];
        const float p0 = phases[n * 4 + c];
        float accA = 0.f, accRe = 0.f, accIm = 0.f;
#pragma unroll
        for (int k = 0; k < K_NEIGH; ++k) {
            const int   idx = nbr_idx[n * 8 + k];
            const float w   = nbr_w[n * 8 + k];
            const float a   = amps[idx * 4 + c];
            const float p   = phases[idx * 4 + c];
            float sp, cp;
            sincosf(p, &sp, &cp);
            accA  = fmaf(w, a,  accA);
            accRe = fmaf(w, cp, accRe);
            accIm = fmaf(w, sp, accIm);
        }
        const float amp_s = 0.8f * a0 + 0.2f * accA;
        float s0, c0;
        sincosf(p0, &s0, &c0);
        const float mre = 0.8f * c0 + 0.2f * accRe;
        const float mim = 0.8f * s0 + 0.2f * accIm;
        const float r2  = mre * mre + mim * mim;
        float cs, cc;
        if (r2 > 1e-30f) {
            // cos(atan2(mim,mre)) = mre/r ; sin(...) = mim/r  -> no atan2/sin/cos
            const float rinv = rsqrtf(r2);
            cs = amp_s * mre * rinv;
            cc = amp_s * mim * rinv;
        } else {
            cs = amp_s;  // atan2(0,0)=0 -> cos=1, sin=0
            cc = 0.f;
        }
        lds_cs[tid] = cs;
        lds_cc[tid] = cc;
    } else if (tid >= 200 && tid < 200 + SPB) {   // 50 threads: offset/trend
        const int s = tid - 200;
        lds_off[s] = constant_offset[n0 + s];
        lds_tr[s]  = linear_trend[n0 + s];
    }
    __syncthreads();

    // ---- Phase C: 9-FMA hot loop, one float4 store per station ----
    if (tid < 250) {
        for (int s = 0; s < SPB; ++s) {
            const int n   = n0 + s;
            const float off = lds_off[s];
            const float tr  = lds_tr[s];
            const float cS0 = lds_cs[s * 4 + 0], cS1 = lds_cs[s * 4 + 1];
            const float cS2 = lds_cs[s * 4 + 2], cS3 = lds_cs[s * 4 + 3];
            const float cC0 = lds_cc[s * 4 + 0], cC1 = lds_cc[s * 4 + 1];
            const float cC2 = lds_cc[s * 4 + 2], cC3 = lds_cc[s * 4 + 3];
            float4 o;
            float* op = &o.x;
#pragma unroll
            for (int j = 0; j < 4; ++j) {
                float v = fmaf(tr, t4[j], off);
                v = fmaf(cS0, stab[0][j], v);
                v = fmaf(cC0, ctab[0][j], v);
                v = fmaf(cS1, stab[1][j], v);
                v = fmaf(cC1, ctab[1][j], v);
                v = fmaf(cS2, stab[2][j], v);
                v = fmaf(cC2, ctab[2][j], v);
                v = fmaf(cS3, stab[3][j], v);
                v = fmaf(cC3, ctab[3][j], v);
                op[j] = v;
            }
            *(float4*)(out + (size_t)n * N_TIME + 4 * tid) = o;
        }
    }
}

extern "C" void kernel_launch(void* const* d_in, const int* in_sizes, int n_in,
                              void* d_out, int out_size, void* d_ws, size_t ws_size,
                              hipStream_t stream) {
    const float* time_vector     = (const float*)d_in[0];
    const float* constant_offset = (const float*)d_in[1];
    const float* linear_trend    = (const float*)d_in[2];
    const float* amps            = (const float*)d_in[3];
    const float* phases          = (const float*)d_in[4];
    const int*   nbr_idx         = (const int*)  d_in[5];
    const float* nbr_w           = (const float*)d_in[6];
    const float* periods         = (const float*)d_in[7];
    float* out = (float*)d_out;

    dim3 grid(N_STATIONS / SPB);   // 2000 blocks
    insar_kernel<<<grid, 256, 0, stream>>>(time_vector, constant_offset, linear_trend,
                                           amps, phases, nbr_idx, nbr_w, periods, out);
}